// Round 5
// baseline (1724.396 us; speedup 1.0000x reference)
//
#include <hip/hip_runtime.h>
#include <math.h>

#define N3 262144           // 64^3

// ===========================================================================
// Derived-feature formulation. emb is zero for r=sqrt(2),sqrt(3) taps, so the
// 27-tap conv is a 7-point stencil. All 6 face taps (r=1) share one embedding
// row -> W_face is tap-independent. sh0=1, sh1(face along A, sign s)=s*sqrt3*e_A,
// sh1(center)=0. Hence per input row the conv depends only on:
//   c   = value at center
//   S   = sum of 6 face neighbors
//   D_A = x(+e_A) - x(-e_A),  A in {d,h,w}
// Output blocks (conv2):
//   scalar->scalar/gate : T2c[i][o]*c + T2f[i][o]*S        (skips folded in T2c)
//   scalar->vector      : T2sv[i][jj] * D_A  -> out[24+3jj+A]
//   vector->scalar      : T2vs[u][o] * D_m of row (u,m)
//   vv0 (+ sc2_v skip)  : T2v0c[u][jj]*c + T2v0f[u][jj]*S -> out[24+3jj+m]
//   vv1 (Levi-Civita)   : +T2v1*D_{(m+1)%3} -> n=(m+2)%3 ; -T2v1*D_{(m+2)%3} -> n=(m+1)%3
// ===========================================================================

// Table layout in floats (global scratch, then staged to LDS):
// conv1 block (448):
//   T1c  [8][24]  @ 0      a1*Wc + sc1/sqrt8
//   T1f  [8][24]  @ 192    a1*Wf
//   T1v  [8][8]   @ 384    a1*sqrt3*Wf_sv
// conv2 block (1280) @ 448:
//   T2c  [16][24] @ +0     a_s*Wc + 0.25*sc2s
//   T2f  [16][24] @ +384   a_s*Wf
//   T2sv [16][8]  @ +768   a_v*sqrt3*Wf_sv
//   T2vs [8][24]  @ +896   a_s3*sqrt3*Wf_{vs|vg}
//   T2v0c[8][8]   @ +1088  a_v*Wc_vv0 + sc2v/sqrt8
//   T2v0f[8][8]   @ +1152  a_v*Wf_vv0
//   T2v1 [8][8]   @ +1216  a_v6*sqrt3*Wf_vv1
#define TBL_TOTAL 1728

__device__ inline void lattice_emb(int p, float* embr) {
    int i = p / 9, j = (p / 3) % 3, k = p % 3;
    float gx = (float)(i - 1), gy = (float)(j - 1), gz = (float)(k - 1);
    float r = sqrtf(gx * gx + gy * gy + gz * gz);
    const float centers[4] = {0.f, 0.33333334f, 0.6666667f, 1.f};
    const float step = 0.33333334f;
    #pragma unroll
    for (int b = 0; b < 4; b++) {
        float dd = (r - centers[b]) / step;
        float e = 0.f;
        if (fabsf(dd) < 1.f)
            e = 1.14136f * expf(2.f) * expf(-1.f / fmaxf(1.f - dd * dd, 1e-9f));
        embr[b] = e;
    }
}

// ---------------------------------------------------------------------------
// Build the derived feature matrices (1728 floats). Grid 7x256.
// ---------------------------------------------------------------------------
__global__ __launch_bounds__(256) void build_tables_kernel(
        const float* __restrict__ w1,  const float* __restrict__ sc1,
        const float* __restrict__ w2,  const float* __restrict__ sc2s,
        const float* __restrict__ sc2v, float* __restrict__ T) {
    int gid = blockIdx.x * 256 + threadIdx.x;
    if (gid >= TBL_TOTAL) return;

    const float inv_ks15 = 0.19245008972987526f;  // 1/3^1.5
    const float s3   = 1.7320508075688772f;
    const float a1   = 0.35355339059327373f;  // 1/sqrt(8)
    const float a_s  = 0.2041241452319315f;   // 1/sqrt(24)
    const float a_v  = 0.17677669529663687f;  // 1/sqrt(32)
    const float a_s3 = 0.11785113019775793f;  // a_s/sqrt(3)
    const float a_v6 = 0.07216878364870322f;  // a_v/sqrt(6)

    float embC[4], embF[4];
    lattice_emb(13, embC);   // center (r=0)
    lattice_emb(22, embF);   // face   (r=1), shared by all 6 faces

    auto WC1 = [&](int c) { float s=0.f;
        #pragma unroll
        for (int b=0;b<4;b++) s += embC[b]*w1[b*256+c]; return s*inv_ks15; };
    auto WF1 = [&](int c) { float s=0.f;
        #pragma unroll
        for (int b=0;b<4;b++) s += embF[b]*w1[b*256+c]; return s*inv_ks15; };
    auto WC2 = [&](int c) { float s=0.f;
        #pragma unroll
        for (int b=0;b<4;b++) s += embC[b]*w2[b*832+c]; return s*inv_ks15; };
    auto WF2 = [&](int c) { float s=0.f;
        #pragma unroll
        for (int b=0;b<4;b++) s += embF[b]*w2[b*832+c]; return s*inv_ks15; };

    float val = 0.f;
    if (gid < 192) {                       // T1c
        int i = gid / 24, o = gid % 24;
        int c = (o < 16) ? i * 16 + o : 128 + i * 8 + (o - 16);
        val = a1 * WC1(c) + a1 * sc1[i * 24 + o];
    } else if (gid < 384) {                // T1f
        int r = gid - 192; int i = r / 24, o = r % 24;
        int c = (o < 16) ? i * 16 + o : 128 + i * 8 + (o - 16);
        val = a1 * WF1(c);
    } else if (gid < 448) {                // T1v
        int r = gid - 384; int i = r / 8, jj = r % 8;
        val = a1 * s3 * WF1(192 + i * 8 + jj);
    } else if (gid < 832) {                // T2c
        int r = gid - 448; int i = r / 24, o = r % 24;
        int c = (o < 16) ? i * 16 + o : 256 + i * 8 + (o - 16);
        val = a_s * WC2(c) + 0.25f * sc2s[i * 24 + o];
    } else if (gid < 1216) {               // T2f
        int r = gid - 832; int i = r / 24, o = r % 24;
        int c = (o < 16) ? i * 16 + o : 256 + i * 8 + (o - 16);
        val = a_s * WF2(c);
    } else if (gid < 1344) {               // T2sv
        int r = gid - 1216; int i = r / 8, jj = r % 8;
        val = a_v * s3 * WF2(384 + i * 8 + jj);
    } else if (gid < 1536) {               // T2vs
        int r = gid - 1344; int u = r / 24, o = r % 24;
        int c = (o < 16) ? 576 + u * 16 + o : 704 + u * 8 + (o - 16);
        val = a_s3 * s3 * WF2(c);
    } else if (gid < 1600) {               // T2v0c
        int r = gid - 1536; int u = r / 8, jj = r % 8;
        val = a_v * WC2(512 + u * 8 + jj) + a1 * sc2v[u * 8 + jj];
    } else if (gid < 1664) {               // T2v0f
        int r = gid - 1600; int u = r / 8, jj = r % 8;
        val = a_v * WF2(512 + u * 8 + jj);
    } else {                               // T2v1
        int r = gid - 1664; int u = r / 8, jj = r % 8;
        val = a_v6 * s3 * WF2(768 + u * 8 + jj);
    }
    T[gid] = val;
}

// ---------------------------------------------------------------------------
// conv1: x(8,64^3) -> ypre(48,64^3). Derived features, fused BN stats.
// ---------------------------------------------------------------------------
__global__ __launch_bounds__(256) void conv1_kernel(const float* __restrict__ x,
                                                    const float* __restrict__ Tg,
                                                    float* __restrict__ out,
                                                    float* __restrict__ stats) {
    __shared__ float T[448];
    __shared__ float red[4][72];
    for (int t = threadIdx.x; t < 448; t += 256) T[t] = Tg[t];
    __syncthreads();

    int idx = blockIdx.x * 256 + threadIdx.x;
    int w = idx & 63, h = (idx >> 6) & 63, d = idx >> 12;
    bool dm = d > 0, dp = d < 63, hm = h > 0, hp = h < 63, wm = w > 0, wp = w < 63;

    float acc[48];
    #pragma unroll
    for (int o = 0; o < 48; o++) acc[o] = 0.f;

    #pragma unroll
    for (int i = 0; i < 8; i++) {
        const float* base = x + i * N3 + idx;
        float c   = base[0];
        float vdm = dm ? base[-4096] : 0.f;
        float vdp = dp ? base[ 4096] : 0.f;
        float vhm = hm ? base[  -64] : 0.f;
        float vhp = hp ? base[   64] : 0.f;
        float vwm = wm ? base[   -1] : 0.f;
        float vwp = wp ? base[    1] : 0.f;
        float S  = vdm + vdp + vhm + vhp + vwm + vwp;
        float Dd = vdp - vdm, Dh = vhp - vhm, Dw = vwp - vwm;

        const float* tc = &T[i * 24];
        const float* tf = &T[192 + i * 24];
        #pragma unroll
        for (int o = 0; o < 24; o++) acc[o] += tc[o] * c + tf[o] * S;
        const float* tv = &T[384 + i * 8];
        #pragma unroll
        for (int jj = 0; jj < 8; jj++) {
            float wv = tv[jj];
            acc[24 + jj * 3 + 0] += wv * Dd;
            acc[24 + jj * 3 + 1] += wv * Dh;
            acc[24 + jj * 3 + 2] += wv * Dw;
        }
    }
    #pragma unroll
    for (int o = 0; o < 48; o++) out[o * N3 + idx] = acc[o];

    // fused BN partial stats: q<24 -> sum(ch q); q in [24,72) -> sumsq(ch q-24)
    int lane = threadIdx.x & 63, wv = threadIdx.x >> 6;
    #pragma unroll
    for (int q = 0; q < 72; q++) {
        float val = (q < 24) ? acc[q] : acc[q - 24] * acc[q - 24];
        #pragma unroll
        for (int m = 32; m >= 1; m >>= 1) val += __shfl_xor(val, m, 64);
        if (lane == 0) red[wv][q] = val;
    }
    __syncthreads();
    if (threadIdx.x < 72) {
        float s = red[0][threadIdx.x] + red[1][threadIdx.x] +
                  red[2][threadIdx.x] + red[3][threadIdx.x];
        atomicAdd(&stats[threadIdx.x], s);
    }
}

// ---------------------------------------------------------------------------
// conv2: y(40,64^3) -> zpre(48,64^3). Derived features, fused BN stats.
// ---------------------------------------------------------------------------
__global__ __launch_bounds__(256) void conv2_kernel(const float* __restrict__ y,
                                                    const float* __restrict__ Tg,
                                                    float* __restrict__ out,
                                                    float* __restrict__ stats) {
    __shared__ float T[1280];
    __shared__ float red[4][72];
    for (int t = threadIdx.x; t < 1280; t += 256) T[t] = Tg[448 + t];
    __syncthreads();

    int idx = blockIdx.x * 256 + threadIdx.x;
    int w = idx & 63, h = (idx >> 6) & 63, d = idx >> 12;
    bool dm = d > 0, dp = d < 63, hm = h > 0, hp = h < 63, wm = w > 0, wp = w < 63;

    float acc[48];
    #pragma unroll
    for (int o = 0; o < 48; o++) acc[o] = 0.f;

    // ---- scalar input rows (16) ----
    #pragma unroll
    for (int i = 0; i < 16; i++) {
        const float* base = y + i * N3 + idx;
        float c   = base[0];
        float vdm = dm ? base[-4096] : 0.f;
        float vdp = dp ? base[ 4096] : 0.f;
        float vhm = hm ? base[  -64] : 0.f;
        float vhp = hp ? base[   64] : 0.f;
        float vwm = wm ? base[   -1] : 0.f;
        float vwp = wp ? base[    1] : 0.f;
        float S  = vdm + vdp + vhm + vhp + vwm + vwp;
        float Dd = vdp - vdm, Dh = vhp - vhm, Dw = vwp - vwm;

        const float* tc = &T[i * 24];
        const float* tf = &T[384 + i * 24];
        #pragma unroll
        for (int o = 0; o < 24; o++) acc[o] += tc[o] * c + tf[o] * S;
        const float* tv = &T[768 + i * 8];
        #pragma unroll
        for (int jj = 0; jj < 8; jj++) {
            float wv = tv[jj];
            acc[24 + jj * 3 + 0] += wv * Dd;
            acc[24 + jj * 3 + 1] += wv * Dh;
            acc[24 + jj * 3 + 2] += wv * Dw;
        }
    }

    // ---- vector input rows (8 x 3) ----
    #pragma unroll
    for (int u = 0; u < 8; u++) {
        #pragma unroll
        for (int m = 0; m < 3; m++) {
            const float* base = y + (16 + u * 3 + m) * N3 + idx;
            float c   = base[0];
            float vdm = dm ? base[-4096] : 0.f;
            float vdp = dp ? base[ 4096] : 0.f;
            float vhm = hm ? base[  -64] : 0.f;
            float vhp = hp ? base[   64] : 0.f;
            float vwm = wm ? base[   -1] : 0.f;
            float vwp = wp ? base[    1] : 0.f;
            float S = vdm + vdp + vhm + vhp + vwm + vwp;
            float D0 = vdp - vdm, D1 = vhp - vhm, D2 = vwp - vwm;
            float Dm = (m == 0) ? D0 : (m == 1) ? D1 : D2;
            float Dp = (m == 0) ? D1 : (m == 1) ? D2 : D0;  // D_{(m+1)%3}
            float Dq = (m == 0) ? D2 : (m == 1) ? D0 : D1;  // D_{(m+2)%3}
            const int n1 = (m + 1) % 3, n2 = (m + 2) % 3;

            const float* tvs = &T[896 + u * 24];
            #pragma unroll
            for (int o = 0; o < 24; o++) acc[o] += tvs[o] * Dm;

            const float* t0c = &T[1088 + u * 8];
            const float* t0f = &T[1152 + u * 8];
            const float* tv1 = &T[1216 + u * 8];
            #pragma unroll
            for (int jj = 0; jj < 8; jj++) {
                acc[24 + jj * 3 + m]  += t0c[jj] * c + t0f[jj] * S;
                float w1v = tv1[jj];
                acc[24 + jj * 3 + n2] += w1v * Dp;
                acc[24 + jj * 3 + n1] -= w1v * Dq;
            }
        }
    }

    #pragma unroll
    for (int o = 0; o < 48; o++) out[o * N3 + idx] = acc[o];

    // fused BN partial stats
    int lane = threadIdx.x & 63, wv = threadIdx.x >> 6;
    #pragma unroll
    for (int q = 0; q < 72; q++) {
        float val = (q < 24) ? acc[q] : acc[q - 24] * acc[q - 24];
        #pragma unroll
        for (int mm = 32; mm >= 1; mm >>= 1) val += __shfl_xor(val, mm, 64);
        if (lane == 0) red[wv][q] = val;
    }
    __syncthreads();
    if (threadIdx.x < 72) {
        float s = red[0][threadIdx.x] + red[1][threadIdx.x] +
                  red[2][threadIdx.x] + red[3][threadIdx.x];
        atomicAdd(&stats[threadIdx.x], s);
    }
}

// ---------------------------------------------------------------------------
// BN apply + gate (finalize inlined): zp(48ch) -> out(40ch), float4/thread
// ---------------------------------------------------------------------------
__global__ __launch_bounds__(256) void bn_gate_kernel(const float* __restrict__ zp,
                                                      const float* __restrict__ stats,
                                                      const float* __restrict__ wsc,
                                                      const float* __restrict__ bsc,
                                                      const float* __restrict__ wvc,
                                                      float* __restrict__ out) {
    __shared__ float sb[56];
    if (threadIdx.x < 32) {
        int t = threadIdx.x;
        const float invN = 1.0f / 262144.0f;
        if (t < 24) {
            float mu = stats[t] * invN;
            float var = stats[24 + t] * invN - mu * mu;
            float inv = rsqrtf(var + 1e-5f);
            sb[t] = wsc[t] * inv;
            sb[24 + t] = bsc[t] - mu * wsc[t] * inv;
        } else {
            int u = t - 24;
            float s2 = stats[48 + u * 3] + stats[48 + u * 3 + 1] + stats[48 + u * 3 + 2];
            sb[48 + u] = wvc[u] * rsqrtf(s2 * invN + 1e-5f);
        }
    }
    __syncthreads();

    int idx = (blockIdx.x * 256 + threadIdx.x) * 4;
    float4 g[8];
    #pragma unroll
    for (int u = 0; u < 8; u++) {
        float4 v = *(const float4*)(zp + (16 + u) * N3 + idx);
        float sc = sb[16 + u], bi = sb[40 + u];
        g[u].x = 1.0f / (1.0f + expf(-(v.x * sc + bi)));
        g[u].y = 1.0f / (1.0f + expf(-(v.y * sc + bi)));
        g[u].z = 1.0f / (1.0f + expf(-(v.z * sc + bi)));
        g[u].w = 1.0f / (1.0f + expf(-(v.w * sc + bi)));
    }
    #pragma unroll
    for (int c = 0; c < 16; c++) {
        float4 v = *(const float4*)(zp + c * N3 + idx);
        float sc = sb[c], bi = sb[24 + c];
        float4 r;
        r.x = fmaxf(v.x * sc + bi, 0.f);
        r.y = fmaxf(v.y * sc + bi, 0.f);
        r.z = fmaxf(v.z * sc + bi, 0.f);
        r.w = fmaxf(v.w * sc + bi, 0.f);
        *(float4*)(out + c * N3 + idx) = r;
    }
    #pragma unroll
    for (int u = 0; u < 8; u++) {
        float sv = sb[48 + u];
        #pragma unroll
        for (int m = 0; m < 3; m++) {
            float4 v = *(const float4*)(zp + (24 + u * 3 + m) * N3 + idx);
            float4 r;
            r.x = v.x * sv * g[u].x;
            r.y = v.y * sv * g[u].y;
            r.z = v.z * sv * g[u].z;
            r.w = v.w * sv * g[u].w;
            *(float4*)(out + (16 + u * 3 + m) * N3 + idx) = r;
        }
    }
}

// ---------------------------------------------------------------------------
extern "C" void kernel_launch(void* const* d_in, const int* in_sizes, int n_in,
                              void* d_out, int out_size, void* d_ws, size_t ws_size,
                              hipStream_t stream) {
    const float* x      = (const float*)d_in[0];
    const float* w1     = (const float*)d_in[1];
    const float* sc1    = (const float*)d_in[2];
    const float* w2     = (const float*)d_in[3];
    const float* sc2s   = (const float*)d_in[4];
    const float* sc2v   = (const float*)d_in[5];
    const float* bn1_ws = (const float*)d_in[6];
    const float* bn1_bs = (const float*)d_in[7];
    const float* bn1_wv = (const float*)d_in[8];
    const float* bn2_ws = (const float*)d_in[9];
    const float* bn2_bs = (const float*)d_in[10];
    const float* bn2_wv = (const float*)d_in[11];
    float* out = (float*)d_out;
    char* ws = (char*)d_ws;

    float* Tg     = (float*)(ws + 0);        // 1728 floats = 6912 B
    float* stats1 = (float*)(ws + 8192);     // 72 floats
    float* stats2 = (float*)(ws + 8192 + 512);
    float* bufA   = (float*)(ws + 262144);   // 48*N3*4 = 50331648 B

    hipMemsetAsync(ws + 8192, 0, 1024, stream);
    hipLaunchKernelGGL(build_tables_kernel, dim3(7), dim3(256), 0, stream,
                       w1, sc1, w2, sc2s, sc2v, Tg);
    hipLaunchKernelGGL(conv1_kernel, dim3(1024), dim3(256), 0, stream, x, Tg, bufA, stats1);
    hipLaunchKernelGGL(bn_gate_kernel, dim3(256), dim3(256), 0, stream,
                       bufA, stats1, bn1_ws, bn1_bs, bn1_wv, out);
    hipLaunchKernelGGL(conv2_kernel, dim3(1024), dim3(256), 0, stream, out, Tg, bufA, stats2);
    hipLaunchKernelGGL(bn_gate_kernel, dim3(256), dim3(256), 0, stream,
                       bufA, stats2, bn2_ws, bn2_bs, bn2_wv, out);
}

// Round 6
// 1103.236 us; speedup vs baseline: 1.5630x; 1.5630x over previous
//
#include <hip/hip_runtime.h>
#include <math.h>

#define N3 262144           // 64^3

// ===========================================================================
// Derived-feature formulation (verified R4/R5): emb==0 for r=sqrt2/sqrt3 taps
// -> 7-point stencil; all 6 face taps share one embedding row. Per input row
// the conv depends only on c (center), S (sum of 6 faces), D_A (axis diffs).
// All acc[] indices MUST be compile-time constants (R5 lesson: runtime index
// -> acc demoted to scratch, 256 VGPR + 3.2 GB spill traffic).
// ===========================================================================

// Table layout (floats):
// conv1 (448): T1c[8][24]@0, T1f[8][24]@192, T1v[8][8]@384
// conv2 (1280)@448: T2c[16][24]@+0, T2f[16][24]@+384, T2sv[16][8]@+768,
//   T2vs[8][24]@+896, T2v0c[8][8]@+1088, T2v0f[8][8]@+1152, T2v1[8][8]@+1216
#define TBL_TOTAL 1728

__device__ inline void lattice_emb(int p, float* embr) {
    int i = p / 9, j = (p / 3) % 3, k = p % 3;
    float gx = (float)(i - 1), gy = (float)(j - 1), gz = (float)(k - 1);
    float r = sqrtf(gx * gx + gy * gy + gz * gz);
    const float centers[4] = {0.f, 0.33333334f, 0.6666667f, 1.f};
    const float step = 0.33333334f;
    #pragma unroll
    for (int b = 0; b < 4; b++) {
        float dd = (r - centers[b]) / step;
        float e = 0.f;
        if (fabsf(dd) < 1.f)
            e = 1.14136f * expf(2.f) * expf(-1.f / fmaxf(1.f - dd * dd, 1e-9f));
        embr[b] = e;
    }
}

// ---------------------------------------------------------------------------
// Build the derived feature matrices (1728 floats).
// ---------------------------------------------------------------------------
__global__ __launch_bounds__(256) void build_tables_kernel(
        const float* __restrict__ w1,  const float* __restrict__ sc1,
        const float* __restrict__ w2,  const float* __restrict__ sc2s,
        const float* __restrict__ sc2v, float* __restrict__ T) {
    int gid = blockIdx.x * 256 + threadIdx.x;
    if (gid >= TBL_TOTAL) return;

    const float inv_ks15 = 0.19245008972987526f;  // 1/3^1.5
    const float s3   = 1.7320508075688772f;
    const float a1   = 0.35355339059327373f;  // 1/sqrt(8)
    const float a_s  = 0.2041241452319315f;   // 1/sqrt(24)
    const float a_v  = 0.17677669529663687f;  // 1/sqrt(32)
    const float a_s3 = 0.11785113019775793f;  // a_s/sqrt(3)
    const float a_v6 = 0.07216878364870322f;  // a_v/sqrt(6)

    float embC[4], embF[4];
    lattice_emb(13, embC);   // center (r=0)
    lattice_emb(22, embF);   // face   (r=1), shared by all 6 faces

    auto WC1 = [&](int c) { float s=0.f;
        #pragma unroll
        for (int b=0;b<4;b++) s += embC[b]*w1[b*256+c]; return s*inv_ks15; };
    auto WF1 = [&](int c) { float s=0.f;
        #pragma unroll
        for (int b=0;b<4;b++) s += embF[b]*w1[b*256+c]; return s*inv_ks15; };
    auto WC2 = [&](int c) { float s=0.f;
        #pragma unroll
        for (int b=0;b<4;b++) s += embC[b]*w2[b*832+c]; return s*inv_ks15; };
    auto WF2 = [&](int c) { float s=0.f;
        #pragma unroll
        for (int b=0;b<4;b++) s += embF[b]*w2[b*832+c]; return s*inv_ks15; };

    float val = 0.f;
    if (gid < 192) {                       // T1c
        int i = gid / 24, o = gid % 24;
        int c = (o < 16) ? i * 16 + o : 128 + i * 8 + (o - 16);
        val = a1 * WC1(c) + a1 * sc1[i * 24 + o];
    } else if (gid < 384) {                // T1f
        int r = gid - 192; int i = r / 24, o = r % 24;
        int c = (o < 16) ? i * 16 + o : 128 + i * 8 + (o - 16);
        val = a1 * WF1(c);
    } else if (gid < 448) {                // T1v
        int r = gid - 384; int i = r / 8, jj = r % 8;
        val = a1 * s3 * WF1(192 + i * 8 + jj);
    } else if (gid < 832) {                // T2c
        int r = gid - 448; int i = r / 24, o = r % 24;
        int c = (o < 16) ? i * 16 + o : 256 + i * 8 + (o - 16);
        val = a_s * WC2(c) + 0.25f * sc2s[i * 24 + o];
    } else if (gid < 1216) {               // T2f
        int r = gid - 832; int i = r / 24, o = r % 24;
        int c = (o < 16) ? i * 16 + o : 256 + i * 8 + (o - 16);
        val = a_s * WF2(c);
    } else if (gid < 1344) {               // T2sv
        int r = gid - 1216; int i = r / 8, jj = r % 8;
        val = a_v * s3 * WF2(384 + i * 8 + jj);
    } else if (gid < 1536) {               // T2vs
        int r = gid - 1344; int u = r / 24, o = r % 24;
        int c = (o < 16) ? 576 + u * 16 + o : 704 + u * 8 + (o - 16);
        val = a_s3 * s3 * WF2(c);
    } else if (gid < 1600) {               // T2v0c
        int r = gid - 1536; int u = r / 8, jj = r % 8;
        val = a_v * WC2(512 + u * 8 + jj) + a1 * sc2v[u * 8 + jj];
    } else if (gid < 1664) {               // T2v0f
        int r = gid - 1600; int u = r / 8, jj = r % 8;
        val = a_v * WF2(512 + u * 8 + jj);
    } else {                               // T2v1
        int r = gid - 1664; int u = r / 8, jj = r % 8;
        val = a_v6 * s3 * WF2(768 + u * 8 + jj);
    }
    T[gid] = val;
}

// Stencil feature loader: c, S=sum of 6 faces, Dd/Dh/Dw axis differences.
#define LOADFEAT(PTR, C_, S_, DD_, DH_, DW_)                                  \
    {                                                                         \
        const float* bp = (PTR);                                              \
        float cc  = bp[0];                                                    \
        float vdm = dmok ? bp[-4096] : 0.f;                                   \
        float vdp = dpok ? bp[ 4096] : 0.f;                                   \
        float vhm = hmok ? bp[  -64] : 0.f;                                   \
        float vhp = hpok ? bp[   64] : 0.f;                                   \
        float vwm = wmok ? bp[   -1] : 0.f;                                   \
        float vwp = wpok ? bp[    1] : 0.f;                                   \
        C_ = cc;                                                              \
        S_ = vdm + vdp + vhm + vhp + vwm + vwp;                               \
        DD_ = vdp - vdm; DH_ = vhp - vhm; DW_ = vwp - vwm;                    \
    }

// ---------------------------------------------------------------------------
// conv1: x(8,64^3) -> ypre(48,64^3). Derived features, fused BN stats.
// ---------------------------------------------------------------------------
__global__ __launch_bounds__(256) void conv1_kernel(const float* __restrict__ x,
                                                    const float* __restrict__ Tg,
                                                    float* __restrict__ out,
                                                    float* __restrict__ stats) {
    __shared__ float T[448];
    __shared__ float red[4][72];
    for (int t = threadIdx.x; t < 448; t += 256) T[t] = Tg[t];
    __syncthreads();

    int idx = blockIdx.x * 256 + threadIdx.x;
    int w = idx & 63, h = (idx >> 6) & 63, d = idx >> 12;
    bool dmok = d > 0, dpok = d < 63, hmok = h > 0, hpok = h < 63,
         wmok = w > 0, wpok = w < 63;

    float acc[48];
    #pragma unroll
    for (int o = 0; o < 48; o++) acc[o] = 0.f;

    #pragma unroll
    for (int i = 0; i < 8; i++) {
        float c, S, Dd, Dh, Dw;
        LOADFEAT(x + i * N3 + idx, c, S, Dd, Dh, Dw);
        const float* tc = &T[i * 24];
        const float* tf = &T[192 + i * 24];
        #pragma unroll
        for (int o = 0; o < 24; o++) acc[o] += tc[o] * c + tf[o] * S;
        const float* tv = &T[384 + i * 8];
        #pragma unroll
        for (int jj = 0; jj < 8; jj++) {
            float wv = tv[jj];
            acc[24 + jj * 3 + 0] += wv * Dd;
            acc[24 + jj * 3 + 1] += wv * Dh;
            acc[24 + jj * 3 + 2] += wv * Dw;
        }
    }
    #pragma unroll
    for (int o = 0; o < 48; o++) out[o * N3 + idx] = acc[o];

    // fused BN partial stats: q<24 -> sum(ch q); q in [24,72) -> sumsq(ch q-24)
    int lane = threadIdx.x & 63, wv = threadIdx.x >> 6;
    #pragma unroll
    for (int q = 0; q < 72; q++) {
        float val = (q < 24) ? acc[q] : acc[q - 24] * acc[q - 24];
        #pragma unroll
        for (int m = 32; m >= 1; m >>= 1) val += __shfl_xor(val, m, 64);
        if (lane == 0) red[wv][q] = val;
    }
    __syncthreads();
    if (threadIdx.x < 72) {
        float s = red[0][threadIdx.x] + red[1][threadIdx.x] +
                  red[2][threadIdx.x] + red[3][threadIdx.x];
        atomicAdd(&stats[threadIdx.x], s);
    }
}

// ---------------------------------------------------------------------------
// conv2: y(40,64^3) -> zpre(48,64^3). Derived features, fully-static acc
// indexing (three vector rows per u expanded to named scalars).
// ---------------------------------------------------------------------------
__global__ __launch_bounds__(256) void conv2_kernel(const float* __restrict__ y,
                                                    const float* __restrict__ Tg,
                                                    float* __restrict__ out,
                                                    float* __restrict__ stats) {
    __shared__ float T[1280];
    __shared__ float red[4][72];
    for (int t = threadIdx.x; t < 1280; t += 256) T[t] = Tg[448 + t];
    __syncthreads();

    int idx = blockIdx.x * 256 + threadIdx.x;
    int w = idx & 63, h = (idx >> 6) & 63, d = idx >> 12;
    bool dmok = d > 0, dpok = d < 63, hmok = h > 0, hpok = h < 63,
         wmok = w > 0, wpok = w < 63;

    float acc[48];
    #pragma unroll
    for (int o = 0; o < 48; o++) acc[o] = 0.f;

    // ---- scalar input rows (16) ----
    #pragma unroll
    for (int i = 0; i < 16; i++) {
        float c, S, Dd, Dh, Dw;
        LOADFEAT(y + i * N3 + idx, c, S, Dd, Dh, Dw);
        const float* tc = &T[i * 24];
        const float* tf = &T[384 + i * 24];
        #pragma unroll
        for (int o = 0; o < 24; o++) acc[o] += tc[o] * c + tf[o] * S;
        const float* tv = &T[768 + i * 8];
        #pragma unroll
        for (int jj = 0; jj < 8; jj++) {
            float wv = tv[jj];
            acc[24 + jj * 3 + 0] += wv * Dd;
            acc[24 + jj * 3 + 1] += wv * Dh;
            acc[24 + jj * 3 + 2] += wv * Dw;
        }
    }

    // ---- vector input rows: per u, 3 rows expanded to named scalars ----
    #pragma unroll
    for (int u = 0; u < 8; u++) {
        float c0, S0, D0_0, D0_1, D0_2;
        float c1, S1, D1_0, D1_1, D1_2;
        float c2, S2, D2_0, D2_1, D2_2;
        LOADFEAT(y + (16 + u * 3 + 0) * N3 + idx, c0, S0, D0_0, D0_1, D0_2);
        LOADFEAT(y + (16 + u * 3 + 1) * N3 + idx, c1, S1, D1_0, D1_1, D1_2);
        LOADFEAT(y + (16 + u * 3 + 2) * N3 + idx, c2, S2, D2_0, D2_1, D2_2);

        // vector->scalar: T2vs[u][o] * sum_m D_m(row m)  (divergence)
        float Dsum = D0_0 + D1_1 + D2_2;
        const float* tvs = &T[896 + u * 24];
        #pragma unroll
        for (int o = 0; o < 24; o++) acc[o] += tvs[o] * Dsum;

        // vv0 + vv1 (Levi-Civita), all indices static:
        // row m contributes: +t0c*c_m,+t0f*S_m to comp m;
        //   +tv1*D_m(axis m+1) to comp (m+2)%3; -tv1*D_m(axis m+2) to comp (m+1)%3
        const float* t0c = &T[1088 + u * 8];
        const float* t0f = &T[1152 + u * 8];
        const float* tv1 = &T[1216 + u * 8];
        #pragma unroll
        for (int jj = 0; jj < 8; jj++) {
            float kc = t0c[jj], kf = t0f[jj], k1 = tv1[jj];
            float a0 = acc[24 + jj * 3 + 0];
            float a1 = acc[24 + jj * 3 + 1];
            float a2 = acc[24 + jj * 3 + 2];
            a0 += kc * c0 + kf * S0;          // m=0 vv0
            a2 += k1 * D0_1; a1 -= k1 * D0_2; // m=0 vv1
            a1 += kc * c1 + kf * S1;          // m=1 vv0
            a0 += k1 * D1_2; a2 -= k1 * D1_0; // m=1 vv1
            a2 += kc * c2 + kf * S2;          // m=2 vv0
            a1 += k1 * D2_0; a0 -= k1 * D2_1; // m=2 vv1
            acc[24 + jj * 3 + 0] = a0;
            acc[24 + jj * 3 + 1] = a1;
            acc[24 + jj * 3 + 2] = a2;
        }
    }

    #pragma unroll
    for (int o = 0; o < 48; o++) out[o * N3 + idx] = acc[o];

    // fused BN partial stats
    int lane = threadIdx.x & 63, wv = threadIdx.x >> 6;
    #pragma unroll
    for (int q = 0; q < 72; q++) {
        float val = (q < 24) ? acc[q] : acc[q - 24] * acc[q - 24];
        #pragma unroll
        for (int mm = 32; mm >= 1; mm >>= 1) val += __shfl_xor(val, mm, 64);
        if (lane == 0) red[wv][q] = val;
    }
    __syncthreads();
    if (threadIdx.x < 72) {
        float s = red[0][threadIdx.x] + red[1][threadIdx.x] +
                  red[2][threadIdx.x] + red[3][threadIdx.x];
        atomicAdd(&stats[threadIdx.x], s);
    }
}

// ---------------------------------------------------------------------------
// BN apply + gate (finalize inlined): zp(48ch) -> out(40ch), float4/thread
// ---------------------------------------------------------------------------
__global__ __launch_bounds__(256) void bn_gate_kernel(const float* __restrict__ zp,
                                                      const float* __restrict__ stats,
                                                      const float* __restrict__ wsc,
                                                      const float* __restrict__ bsc,
                                                      const float* __restrict__ wvc,
                                                      float* __restrict__ out) {
    __shared__ float sb[56];
    if (threadIdx.x < 32) {
        int t = threadIdx.x;
        const float invN = 1.0f / 262144.0f;
        if (t < 24) {
            float mu = stats[t] * invN;
            float var = stats[24 + t] * invN - mu * mu;
            float inv = rsqrtf(var + 1e-5f);
            sb[t] = wsc[t] * inv;
            sb[24 + t] = bsc[t] - mu * wsc[t] * inv;
        } else {
            int u = t - 24;
            float s2 = stats[48 + u * 3] + stats[48 + u * 3 + 1] + stats[48 + u * 3 + 2];
            sb[48 + u] = wvc[u] * rsqrtf(s2 * invN + 1e-5f);
        }
    }
    __syncthreads();

    int idx = (blockIdx.x * 256 + threadIdx.x) * 4;
    float4 g[8];
    #pragma unroll
    for (int u = 0; u < 8; u++) {
        float4 v = *(const float4*)(zp + (16 + u) * N3 + idx);
        float sc = sb[16 + u], bi = sb[40 + u];
        g[u].x = 1.0f / (1.0f + expf(-(v.x * sc + bi)));
        g[u].y = 1.0f / (1.0f + expf(-(v.y * sc + bi)));
        g[u].z = 1.0f / (1.0f + expf(-(v.z * sc + bi)));
        g[u].w = 1.0f / (1.0f + expf(-(v.w * sc + bi)));
    }
    #pragma unroll
    for (int c = 0; c < 16; c++) {
        float4 v = *(const float4*)(zp + c * N3 + idx);
        float sc = sb[c], bi = sb[24 + c];
        float4 r;
        r.x = fmaxf(v.x * sc + bi, 0.f);
        r.y = fmaxf(v.y * sc + bi, 0.f);
        r.z = fmaxf(v.z * sc + bi, 0.f);
        r.w = fmaxf(v.w * sc + bi, 0.f);
        *(float4*)(out + c * N3 + idx) = r;
    }
    #pragma unroll
    for (int u = 0; u < 8; u++) {
        float sv = sb[48 + u];
        #pragma unroll
        for (int m = 0; m < 3; m++) {
            float4 v = *(const float4*)(zp + (24 + u * 3 + m) * N3 + idx);
            float4 r;
            r.x = v.x * sv * g[u].x;
            r.y = v.y * sv * g[u].y;
            r.z = v.z * sv * g[u].z;
            r.w = v.w * sv * g[u].w;
            *(float4*)(out + (16 + u * 3 + m) * N3 + idx) = r;
        }
    }
}

// ---------------------------------------------------------------------------
extern "C" void kernel_launch(void* const* d_in, const int* in_sizes, int n_in,
                              void* d_out, int out_size, void* d_ws, size_t ws_size,
                              hipStream_t stream) {
    const float* x      = (const float*)d_in[0];
    const float* w1     = (const float*)d_in[1];
    const float* sc1    = (const float*)d_in[2];
    const float* w2     = (const float*)d_in[3];
    const float* sc2s   = (const float*)d_in[4];
    const float* sc2v   = (const float*)d_in[5];
    const float* bn1_ws = (const float*)d_in[6];
    const float* bn1_bs = (const float*)d_in[7];
    const float* bn1_wv = (const float*)d_in[8];
    const float* bn2_ws = (const float*)d_in[9];
    const float* bn2_bs = (const float*)d_in[10];
    const float* bn2_wv = (const float*)d_in[11];
    float* out = (float*)d_out;
    char* ws = (char*)d_ws;

    float* Tg     = (float*)(ws + 0);        // 1728 floats = 6912 B
    float* stats1 = (float*)(ws + 8192);     // 72 floats
    float* stats2 = (float*)(ws + 8192 + 512);
    float* bufA   = (float*)(ws + 262144);   // 48*N3*4 = 50331648 B

    hipMemsetAsync(ws + 8192, 0, 1024, stream);
    hipLaunchKernelGGL(build_tables_kernel, dim3(7), dim3(256), 0, stream,
                       w1, sc1, w2, sc2s, sc2v, Tg);
    hipLaunchKernelGGL(conv1_kernel, dim3(1024), dim3(256), 0, stream, x, Tg, bufA, stats1);
    hipLaunchKernelGGL(bn_gate_kernel, dim3(256), dim3(256), 0, stream,
                       bufA, stats1, bn1_ws, bn1_bs, bn1_wv, out);
    hipLaunchKernelGGL(conv2_kernel, dim3(1024), dim3(256), 0, stream, out, Tg, bufA, stats2);
    hipLaunchKernelGGL(bn_gate_kernel, dim3(256), dim3(256), 0, stream,
                       bufA, stats2, bn2_ws, bn2_bs, bn2_wv, out);
}

// Round 7
// 158.668 us; speedup vs baseline: 10.8680x; 6.9531x over previous
//
#include <hip/hip_runtime.h>
#include <math.h>

#define N3 262144           // 64^3

// ===========================================================================
// Derived-feature formulation (verified R4-R6): emb==0 for r=sqrt2/sqrt3 taps
// -> 7-point stencil; all 6 face taps share one embedding row. Per input row
// the conv depends only on c (center), S (sum of 6 faces), D_A (axis diffs).
// Lessons baked in:
//  - R5: acc[] indices must be compile-time constants (else scratch demotion).
//  - R6: row loops must be #pragma unroll 1 — full unroll of 40 rows x 7 loads
//    lets the scheduler hoist loads until live set > 256 VGPR -> spill.
// ===========================================================================

// Table layout (floats):
// conv1 (448): T1c[8][24]@0, T1f[8][24]@192, T1v[8][8]@384
// conv2 (1280)@448: T2c[16][24]@+0, T2f[16][24]@+384, T2sv[16][8]@+768,
//   T2vs[8][24]@+896, T2v0c[8][8]@+1088, T2v0f[8][8]@+1152, T2v1[8][8]@+1216
#define TBL_TOTAL 1728

__device__ inline void lattice_emb(int p, float* embr) {
    int i = p / 9, j = (p / 3) % 3, k = p % 3;
    float gx = (float)(i - 1), gy = (float)(j - 1), gz = (float)(k - 1);
    float r = sqrtf(gx * gx + gy * gy + gz * gz);
    const float centers[4] = {0.f, 0.33333334f, 0.6666667f, 1.f};
    const float step = 0.33333334f;
    #pragma unroll
    for (int b = 0; b < 4; b++) {
        float dd = (r - centers[b]) / step;
        float e = 0.f;
        if (fabsf(dd) < 1.f)
            e = 1.14136f * expf(2.f) * expf(-1.f / fmaxf(1.f - dd * dd, 1e-9f));
        embr[b] = e;
    }
}

// ---------------------------------------------------------------------------
// Build the derived feature matrices (1728 floats).
// ---------------------------------------------------------------------------
__global__ __launch_bounds__(256) void build_tables_kernel(
        const float* __restrict__ w1,  const float* __restrict__ sc1,
        const float* __restrict__ w2,  const float* __restrict__ sc2s,
        const float* __restrict__ sc2v, float* __restrict__ T) {
    int gid = blockIdx.x * 256 + threadIdx.x;
    if (gid >= TBL_TOTAL) return;

    const float inv_ks15 = 0.19245008972987526f;  // 1/3^1.5
    const float s3   = 1.7320508075688772f;
    const float a1   = 0.35355339059327373f;  // 1/sqrt(8)
    const float a_s  = 0.2041241452319315f;   // 1/sqrt(24)
    const float a_v  = 0.17677669529663687f;  // 1/sqrt(32)
    const float a_s3 = 0.11785113019775793f;  // a_s/sqrt(3)
    const float a_v6 = 0.07216878364870322f;  // a_v/sqrt(6)

    float embC[4], embF[4];
    lattice_emb(13, embC);   // center (r=0)
    lattice_emb(22, embF);   // face   (r=1), shared by all 6 faces

    auto WC1 = [&](int c) { float s=0.f;
        #pragma unroll
        for (int b=0;b<4;b++) s += embC[b]*w1[b*256+c]; return s*inv_ks15; };
    auto WF1 = [&](int c) { float s=0.f;
        #pragma unroll
        for (int b=0;b<4;b++) s += embF[b]*w1[b*256+c]; return s*inv_ks15; };
    auto WC2 = [&](int c) { float s=0.f;
        #pragma unroll
        for (int b=0;b<4;b++) s += embC[b]*w2[b*832+c]; return s*inv_ks15; };
    auto WF2 = [&](int c) { float s=0.f;
        #pragma unroll
        for (int b=0;b<4;b++) s += embF[b]*w2[b*832+c]; return s*inv_ks15; };

    float val = 0.f;
    if (gid < 192) {                       // T1c
        int i = gid / 24, o = gid % 24;
        int c = (o < 16) ? i * 16 + o : 128 + i * 8 + (o - 16);
        val = a1 * WC1(c) + a1 * sc1[i * 24 + o];
    } else if (gid < 384) {                // T1f
        int r = gid - 192; int i = r / 24, o = r % 24;
        int c = (o < 16) ? i * 16 + o : 128 + i * 8 + (o - 16);
        val = a1 * WF1(c);
    } else if (gid < 448) {                // T1v
        int r = gid - 384; int i = r / 8, jj = r % 8;
        val = a1 * s3 * WF1(192 + i * 8 + jj);
    } else if (gid < 832) {                // T2c
        int r = gid - 448; int i = r / 24, o = r % 24;
        int c = (o < 16) ? i * 16 + o : 256 + i * 8 + (o - 16);
        val = a_s * WC2(c) + 0.25f * sc2s[i * 24 + o];
    } else if (gid < 1216) {               // T2f
        int r = gid - 832; int i = r / 24, o = r % 24;
        int c = (o < 16) ? i * 16 + o : 256 + i * 8 + (o - 16);
        val = a_s * WF2(c);
    } else if (gid < 1344) {               // T2sv
        int r = gid - 1216; int i = r / 8, jj = r % 8;
        val = a_v * s3 * WF2(384 + i * 8 + jj);
    } else if (gid < 1536) {               // T2vs
        int r = gid - 1344; int u = r / 24, o = r % 24;
        int c = (o < 16) ? 576 + u * 16 + o : 704 + u * 8 + (o - 16);
        val = a_s3 * s3 * WF2(c);
    } else if (gid < 1600) {               // T2v0c
        int r = gid - 1536; int u = r / 8, jj = r % 8;
        val = a_v * WC2(512 + u * 8 + jj) + a1 * sc2v[u * 8 + jj];
    } else if (gid < 1664) {               // T2v0f
        int r = gid - 1600; int u = r / 8, jj = r % 8;
        val = a_v * WF2(512 + u * 8 + jj);
    } else {                               // T2v1
        int r = gid - 1664; int u = r / 8, jj = r % 8;
        val = a_v6 * s3 * WF2(768 + u * 8 + jj);
    }
    T[gid] = val;
}

// Stencil feature loader: c, S=sum of 6 faces, Dd/Dh/Dw axis differences.
#define LOADFEAT(PTR, C_, S_, DD_, DH_, DW_)                                  \
    {                                                                         \
        const float* bp = (PTR);                                              \
        float cc  = bp[0];                                                    \
        float vdm = dmok ? bp[-4096] : 0.f;                                   \
        float vdp = dpok ? bp[ 4096] : 0.f;                                   \
        float vhm = hmok ? bp[  -64] : 0.f;                                   \
        float vhp = hpok ? bp[   64] : 0.f;                                   \
        float vwm = wmok ? bp[   -1] : 0.f;                                   \
        float vwp = wpok ? bp[    1] : 0.f;                                   \
        C_ = cc;                                                              \
        S_ = vdm + vdp + vhm + vhp + vwm + vwp;                               \
        DD_ = vdp - vdm; DH_ = vhp - vhm; DW_ = vwp - vwm;                    \
    }

// ---------------------------------------------------------------------------
// conv1: x(8,64^3) -> ypre(48,64^3). Derived features, fused BN stats.
// ---------------------------------------------------------------------------
__global__ __launch_bounds__(256) void conv1_kernel(const float* __restrict__ x,
                                                    const float* __restrict__ Tg,
                                                    float* __restrict__ out,
                                                    float* __restrict__ stats) {
    __shared__ float T[448];
    __shared__ float red[4][72];
    for (int t = threadIdx.x; t < 448; t += 256) T[t] = Tg[t];
    __syncthreads();

    int idx = blockIdx.x * 256 + threadIdx.x;
    int w = idx & 63, h = (idx >> 6) & 63, d = idx >> 12;
    bool dmok = d > 0, dpok = d < 63, hmok = h > 0, hpok = h < 63,
         wmok = w > 0, wpok = w < 63;

    float acc[48];
    #pragma unroll
    for (int o = 0; o < 48; o++) acc[o] = 0.f;

    #pragma unroll 1
    for (int i = 0; i < 8; i++) {
        float c, S, Dd, Dh, Dw;
        LOADFEAT(x + i * N3 + idx, c, S, Dd, Dh, Dw);
        const float* tc = &T[i * 24];
        const float* tf = &T[192 + i * 24];
        #pragma unroll
        for (int o = 0; o < 24; o++) acc[o] += tc[o] * c + tf[o] * S;
        const float* tv = &T[384 + i * 8];
        #pragma unroll
        for (int jj = 0; jj < 8; jj++) {
            float wv = tv[jj];
            acc[24 + jj * 3 + 0] += wv * Dd;
            acc[24 + jj * 3 + 1] += wv * Dh;
            acc[24 + jj * 3 + 2] += wv * Dw;
        }
    }
    #pragma unroll
    for (int o = 0; o < 48; o++) out[o * N3 + idx] = acc[o];

    // fused BN partial stats: q<24 -> sum(ch q); q in [24,72) -> sumsq(ch q-24)
    int lane = threadIdx.x & 63, wv = threadIdx.x >> 6;
    #pragma unroll
    for (int q = 0; q < 72; q++) {
        float val = (q < 24) ? acc[q] : acc[q - 24] * acc[q - 24];
        #pragma unroll
        for (int m = 32; m >= 1; m >>= 1) val += __shfl_xor(val, m, 64);
        if (lane == 0) red[wv][q] = val;
    }
    __syncthreads();
    if (threadIdx.x < 72) {
        float s = red[0][threadIdx.x] + red[1][threadIdx.x] +
                  red[2][threadIdx.x] + red[3][threadIdx.x];
        atomicAdd(&stats[threadIdx.x], s);
    }
}

// ---------------------------------------------------------------------------
// conv2: y(40,64^3) -> zpre(48,64^3). Derived features; row loops kept
// runtime (#pragma unroll 1) to bound register pressure.
// ---------------------------------------------------------------------------
__global__ __launch_bounds__(256) void conv2_kernel(const float* __restrict__ y,
                                                    const float* __restrict__ Tg,
                                                    float* __restrict__ out,
                                                    float* __restrict__ stats) {
    __shared__ float T[1280];
    __shared__ float red[4][72];
    for (int t = threadIdx.x; t < 1280; t += 256) T[t] = Tg[448 + t];
    __syncthreads();

    int idx = blockIdx.x * 256 + threadIdx.x;
    int w = idx & 63, h = (idx >> 6) & 63, d = idx >> 12;
    bool dmok = d > 0, dpok = d < 63, hmok = h > 0, hpok = h < 63,
         wmok = w > 0, wpok = w < 63;

    float acc[48];
    #pragma unroll
    for (int o = 0; o < 48; o++) acc[o] = 0.f;

    // ---- scalar input rows (16) ----
    #pragma unroll 1
    for (int i = 0; i < 16; i++) {
        float c, S, Dd, Dh, Dw;
        LOADFEAT(y + i * N3 + idx, c, S, Dd, Dh, Dw);
        const float* tc = &T[i * 24];
        const float* tf = &T[384 + i * 24];
        #pragma unroll
        for (int o = 0; o < 24; o++) acc[o] += tc[o] * c + tf[o] * S;
        const float* tv = &T[768 + i * 8];
        #pragma unroll
        for (int jj = 0; jj < 8; jj++) {
            float wv = tv[jj];
            acc[24 + jj * 3 + 0] += wv * Dd;
            acc[24 + jj * 3 + 1] += wv * Dh;
            acc[24 + jj * 3 + 2] += wv * Dw;
        }
    }

    // ---- vector input rows: per u, 3 rows expanded to named scalars ----
    #pragma unroll 1
    for (int u = 0; u < 8; u++) {
        float c0, S0, D0_0, D0_1, D0_2;
        float c1, S1, D1_0, D1_1, D1_2;
        float c2, S2, D2_0, D2_1, D2_2;
        LOADFEAT(y + (16 + u * 3 + 0) * N3 + idx, c0, S0, D0_0, D0_1, D0_2);
        LOADFEAT(y + (16 + u * 3 + 1) * N3 + idx, c1, S1, D1_0, D1_1, D1_2);
        LOADFEAT(y + (16 + u * 3 + 2) * N3 + idx, c2, S2, D2_0, D2_1, D2_2);

        // vector->scalar: T2vs[u][o] * divergence
        float Dsum = D0_0 + D1_1 + D2_2;
        const float* tvs = &T[896 + u * 24];
        #pragma unroll
        for (int o = 0; o < 24; o++) acc[o] += tvs[o] * Dsum;

        // vv0 + vv1 (Levi-Civita), all acc indices static
        const float* t0c = &T[1088 + u * 8];
        const float* t0f = &T[1152 + u * 8];
        const float* tv1 = &T[1216 + u * 8];
        #pragma unroll
        for (int jj = 0; jj < 8; jj++) {
            float kc = t0c[jj], kf = t0f[jj], k1 = tv1[jj];
            float a0 = acc[24 + jj * 3 + 0];
            float a1 = acc[24 + jj * 3 + 1];
            float a2 = acc[24 + jj * 3 + 2];
            a0 += kc * c0 + kf * S0;          // m=0 vv0
            a2 += k1 * D0_1; a1 -= k1 * D0_2; // m=0 vv1
            a1 += kc * c1 + kf * S1;          // m=1 vv0
            a0 += k1 * D1_2; a2 -= k1 * D1_0; // m=1 vv1
            a2 += kc * c2 + kf * S2;          // m=2 vv0
            a1 += k1 * D2_0; a0 -= k1 * D2_1; // m=2 vv1
            acc[24 + jj * 3 + 0] = a0;
            acc[24 + jj * 3 + 1] = a1;
            acc[24 + jj * 3 + 2] = a2;
        }
    }

    #pragma unroll
    for (int o = 0; o < 48; o++) out[o * N3 + idx] = acc[o];

    // fused BN partial stats
    int lane = threadIdx.x & 63, wv = threadIdx.x >> 6;
    #pragma unroll
    for (int q = 0; q < 72; q++) {
        float val = (q < 24) ? acc[q] : acc[q - 24] * acc[q - 24];
        #pragma unroll
        for (int mm = 32; mm >= 1; mm >>= 1) val += __shfl_xor(val, mm, 64);
        if (lane == 0) red[wv][q] = val;
    }
    __syncthreads();
    if (threadIdx.x < 72) {
        float s = red[0][threadIdx.x] + red[1][threadIdx.x] +
                  red[2][threadIdx.x] + red[3][threadIdx.x];
        atomicAdd(&stats[threadIdx.x], s);
    }
}

// ---------------------------------------------------------------------------
// BN apply + gate (finalize inlined): zp(48ch) -> out(40ch), float4/thread
// ---------------------------------------------------------------------------
__global__ __launch_bounds__(256) void bn_gate_kernel(const float* __restrict__ zp,
                                                      const float* __restrict__ stats,
                                                      const float* __restrict__ wsc,
                                                      const float* __restrict__ bsc,
                                                      const float* __restrict__ wvc,
                                                      float* __restrict__ out) {
    __shared__ float sb[56];
    if (threadIdx.x < 32) {
        int t = threadIdx.x;
        const float invN = 1.0f / 262144.0f;
        if (t < 24) {
            float mu = stats[t] * invN;
            float var = stats[24 + t] * invN - mu * mu;
            float inv = rsqrtf(var + 1e-5f);
            sb[t] = wsc[t] * inv;
            sb[24 + t] = bsc[t] - mu * wsc[t] * inv;
        } else {
            int u = t - 24;
            float s2 = stats[48 + u * 3] + stats[48 + u * 3 + 1] + stats[48 + u * 3 + 2];
            sb[48 + u] = wvc[u] * rsqrtf(s2 * invN + 1e-5f);
        }
    }
    __syncthreads();

    int idx = (blockIdx.x * 256 + threadIdx.x) * 4;
    float4 g[8];
    #pragma unroll
    for (int u = 0; u < 8; u++) {
        float4 v = *(const float4*)(zp + (16 + u) * N3 + idx);
        float sc = sb[16 + u], bi = sb[40 + u];
        g[u].x = 1.0f / (1.0f + expf(-(v.x * sc + bi)));
        g[u].y = 1.0f / (1.0f + expf(-(v.y * sc + bi)));
        g[u].z = 1.0f / (1.0f + expf(-(v.z * sc + bi)));
        g[u].w = 1.0f / (1.0f + expf(-(v.w * sc + bi)));
    }
    #pragma unroll
    for (int c = 0; c < 16; c++) {
        float4 v = *(const float4*)(zp + c * N3 + idx);
        float sc = sb[c], bi = sb[24 + c];
        float4 r;
        r.x = fmaxf(v.x * sc + bi, 0.f);
        r.y = fmaxf(v.y * sc + bi, 0.f);
        r.z = fmaxf(v.z * sc + bi, 0.f);
        r.w = fmaxf(v.w * sc + bi, 0.f);
        *(float4*)(out + c * N3 + idx) = r;
    }
    #pragma unroll
    for (int u = 0; u < 8; u++) {
        float sv = sb[48 + u];
        #pragma unroll
        for (int m = 0; m < 3; m++) {
            float4 v = *(const float4*)(zp + (24 + u * 3 + m) * N3 + idx);
            float4 r;
            r.x = v.x * sv * g[u].x;
            r.y = v.y * sv * g[u].y;
            r.z = v.z * sv * g[u].z;
            r.w = v.w * sv * g[u].w;
            *(float4*)(out + (16 + u * 3 + m) * N3 + idx) = r;
        }
    }
}

// ---------------------------------------------------------------------------
extern "C" void kernel_launch(void* const* d_in, const int* in_sizes, int n_in,
                              void* d_out, int out_size, void* d_ws, size_t ws_size,
                              hipStream_t stream) {
    const float* x      = (const float*)d_in[0];
    const float* w1     = (const float*)d_in[1];
    const float* sc1    = (const float*)d_in[2];
    const float* w2     = (const float*)d_in[3];
    const float* sc2s   = (const float*)d_in[4];
    const float* sc2v   = (const float*)d_in[5];
    const float* bn1_ws = (const float*)d_in[6];
    const float* bn1_bs = (const float*)d_in[7];
    const float* bn1_wv = (const float*)d_in[8];
    const float* bn2_ws = (const float*)d_in[9];
    const float* bn2_bs = (const float*)d_in[10];
    const float* bn2_wv = (const float*)d_in[11];
    float* out = (float*)d_out;
    char* ws = (char*)d_ws;

    float* Tg     = (float*)(ws + 0);        // 1728 floats = 6912 B
    float* stats1 = (float*)(ws + 8192);     // 72 floats
    float* stats2 = (float*)(ws + 8192 + 512);
    float* bufA   = (float*)(ws + 262144);   // 48*N3*4 = 50331648 B

    hipMemsetAsync(ws + 8192, 0, 1024, stream);
    hipLaunchKernelGGL(build_tables_kernel, dim3(7), dim3(256), 0, stream,
                       w1, sc1, w2, sc2s, sc2v, Tg);
    hipLaunchKernelGGL(conv1_kernel, dim3(1024), dim3(256), 0, stream, x, Tg, bufA, stats1);
    hipLaunchKernelGGL(bn_gate_kernel, dim3(256), dim3(256), 0, stream,
                       bufA, stats1, bn1_ws, bn1_bs, bn1_wv, out);
    hipLaunchKernelGGL(conv2_kernel, dim3(1024), dim3(256), 0, stream, out, Tg, bufA, stats2);
    hipLaunchKernelGGL(bn_gate_kernel, dim3(256), dim3(256), 0, stream,
                       bufA, stats2, bn2_ws, bn2_bs, bn2_wv, out);
}